// Round 1
// baseline (731.428 us; speedup 1.0000x reference)
//
#include <hip/hip_runtime.h>
#include <cstdint>
#include <cstddef>

typedef unsigned short u16;
typedef __attribute__((ext_vector_type(4))) float f32x4;
typedef __attribute__((ext_vector_type(8))) short s16x8;

#define BB 8
#define SS 2048
#define DD 1024
#define FF 3072
#define MM (BB*SS)      // 16384 tokens
#define NCH 32          // scan chunks
#define LCH (SS/NCH)    // 64 steps per chunk

__device__ __forceinline__ float bf2f(u16 u){ union{uint32_t i;float f;}v; v.i=((uint32_t)u)<<16; return v.f; }
__device__ __forceinline__ u16 f2bf(float f){ union{float f;uint32_t i;}v; v.f=f; uint32_t r=v.i+0x7FFFu+((v.i>>16)&1u); return (u16)(r>>16); }
__device__ __forceinline__ float sigm(float x){ return 1.f/(1.f+__expf(-x)); }
__device__ __forceinline__ float tanh_f(float x){ return 2.f*sigm(2.f*x)-1.f; }

// ---------------- weight conversion ----------------
// Wg,Wv,Wd [1024,1024] f32 -> stacked [3072,1024] bf16
__global__ void conv_gvd(const float* __restrict__ Wg, const float* __restrict__ Wv,
                         const float* __restrict__ Wd, u16* __restrict__ out){
  size_t i = ((size_t)blockIdx.x*256 + threadIdx.x)*4;
  int row = (int)(i >> 10); int col = (int)(i & 1023);
  const float* src; int srow;
  if (row < 1024)      { src = Wg; srow = row; }
  else if (row < 2048) { src = Wv; srow = row-1024; }
  else                 { src = Wd; srow = row-2048; }
  float4 v = *(const float4*)(src + (size_t)srow*1024 + col);
  ushort4 o; o.x=f2bf(v.x); o.y=f2bf(v.y); o.z=f2bf(v.z); o.w=f2bf(v.w);
  *(ushort4*)(out + i) = o;
}

// W_gate,W_up [3072,1024] -> interleaved [6144,1024] bf16:
// rows [32g..32g+15] = W_gate[16g..16g+15], rows [32g+16..32g+31] = W_up[16g..16g+15]
__global__ void conv_gu(const float* __restrict__ Wgate, const float* __restrict__ Wup,
                        u16* __restrict__ out){
  size_t i = ((size_t)blockIdx.x*256 + threadIdx.x)*4;
  int row = (int)(i >> 10); int col = (int)(i & 1023);
  int group = row >> 5, w = row & 31;
  const float* src = (w < 16) ? Wgate : Wup;
  int srow = group*16 + (w & 15);
  float4 v = *(const float4*)(src + (size_t)srow*1024 + col);
  ushort4 o; o.x=f2bf(v.x); o.y=f2bf(v.y); o.z=f2bf(v.z); o.w=f2bf(v.w);
  *(ushort4*)(out + i) = o;
}

// W_out [1024,3072] f32 -> bf16
__global__ void conv_cp(const float* __restrict__ W, u16* __restrict__ out){
  size_t i = ((size_t)blockIdx.x*256 + threadIdx.x)*4;
  float4 v = *(const float4*)(W + i);
  ushort4 o; o.x=f2bf(v.x); o.y=f2bf(v.y); o.z=f2bf(v.z); o.w=f2bf(v.w);
  *(ushort4*)(out + i) = o;
}

// ---------------- RMSNorm: f32 [M,1024] -> bf16 [M,1024] ----------------
__global__ void rmsnorm_k(const float* __restrict__ x, const float* __restrict__ wgt,
                          u16* __restrict__ out){
  const int row = blockIdx.x, t = threadIdx.x;
  float4 v = ((const float4*)(x + (size_t)row*DD))[t];
  float ss = v.x*v.x + v.y*v.y + v.z*v.z + v.w*v.w;
  #pragma unroll
  for (int o = 32; o > 0; o >>= 1) ss += __shfl_down(ss, o, 64);
  __shared__ float sacc[4];
  if ((t & 63) == 0) sacc[t >> 6] = ss;
  __syncthreads();
  float tot = sacc[0] + sacc[1] + sacc[2] + sacc[3];
  float r = rsqrtf(tot * (1.f/(float)DD) + 1e-6f);
  float4 wv = ((const float4*)wgt)[t];
  ushort4 o; o.x=f2bf(v.x*r*wv.x); o.y=f2bf(v.y*r*wv.y); o.z=f2bf(v.z*r*wv.z); o.w=f2bf(v.w*r*wv.w);
  ((ushort4*)(out + (size_t)row*DD))[t] = o;
}

// ---------------- GEMM: C[M,N] = A[M,K] * B[N,K]^T, bf16 in, f32 acc ----------------
// 128x128 tile, BK=32, 4 waves (2x2), each wave 64x64 = 4x4 fragments of 16x16x32.
// EPI 0: gvd epilogue (sigmoid/tanh/decay + bias), EPI 1: SwiGLU pairing -> h bf16,
// EPI 2: out += acc (residual already in o_y).
template<int EPI>
__global__ __launch_bounds__(256) void gemm_bt(
    const u16* __restrict__ A, const u16* __restrict__ Bm, int K,
    const float* __restrict__ bg, const float* __restrict__ bv, const float* __restrict__ bd,
    u16* __restrict__ o_sg, u16* __restrict__ o_tv, float* __restrict__ o_a,
    u16* __restrict__ o_h, float* __restrict__ o_y)
{
  __shared__ u16 lds[2][2][128*32];
  const int tm = blockIdx.x, tn = blockIdx.y;
  const int t = threadIdx.x, w = t >> 6, l = t & 63;
  const int srow = (w << 4) + (l >> 2);      // staging row (+64 for 2nd inst)
  const int scol = (l & 3) << 3;             // staging k-offset (8 bf16)
  const int wrow = ((w >> 1) << 6), wcol = ((w & 1) << 6);

  const u16* ga = A  + (size_t)(tm*128 + srow)*K + scol;
  const u16* gb = Bm + (size_t)(tn*128 + srow)*K + scol;

#define STAGE(buf, kt) do { \
    const u16* pa_ = ga + (size_t)(kt)*32; \
    const u16* pb_ = gb + (size_t)(kt)*32; \
    __builtin_amdgcn_global_load_lds((const __attribute__((address_space(1))) void*)pa_,                   (__attribute__((address_space(3))) void*)&lds[buf][0][w*512],        16, 0, 0); \
    __builtin_amdgcn_global_load_lds((const __attribute__((address_space(1))) void*)(pa_ + (size_t)64*K), (__attribute__((address_space(3))) void*)&lds[buf][0][2048 + w*512], 16, 0, 0); \
    __builtin_amdgcn_global_load_lds((const __attribute__((address_space(1))) void*)pb_,                   (__attribute__((address_space(3))) void*)&lds[buf][1][w*512],        16, 0, 0); \
    __builtin_amdgcn_global_load_lds((const __attribute__((address_space(1))) void*)(pb_ + (size_t)64*K), (__attribute__((address_space(3))) void*)&lds[buf][1][2048 + w*512], 16, 0, 0); \
  } while(0)

  f32x4 acc[4][4] = {};
  const int nk = K / 32;
  STAGE(0, 0);
  asm volatile("s_waitcnt vmcnt(0)" ::: "memory");
  __syncthreads();

  const int ro = ((l & 15) << 5) + ((l >> 4) << 3);  // (row-in-frag)*32 + kslice*8
  for (int kt = 0; kt < nk; ++kt){
    const int cur = kt & 1;
    if (kt + 1 < nk) STAGE(cur ^ 1, kt + 1);
    s16x8 af[4], bfr[4];
    #pragma unroll
    for (int m = 0; m < 4; ++m) af[m]  = *(const s16x8*)&lds[cur][0][((wrow + (m<<4)) << 5) + ro];
    #pragma unroll
    for (int n = 0; n < 4; ++n) bfr[n] = *(const s16x8*)&lds[cur][1][((wcol + (n<<4)) << 5) + ro];
    #pragma unroll
    for (int m = 0; m < 4; ++m)
      #pragma unroll
      for (int n = 0; n < 4; ++n)
        acc[m][n] = __builtin_amdgcn_mfma_f32_16x16x32_bf16(af[m], bfr[n], acc[m][n], 0, 0, 0);
    asm volatile("s_waitcnt vmcnt(0)" ::: "memory");
    __syncthreads();
  }
#undef STAGE

  const int rbase = tm*128 + wrow + ((l >> 4) << 2);
  const int cbase = tn*128 + wcol + (l & 15);
  if constexpr (EPI == 0) {
    #pragma unroll
    for (int m = 0; m < 4; ++m)
      #pragma unroll
      for (int n = 0; n < 4; ++n) {
        int c = cbase + n*16;
        #pragma unroll
        for (int i = 0; i < 4; ++i) {
          int r = rbase + m*16 + i;
          float v = acc[m][n][i];
          if (c < 1024)      o_sg[(size_t)r*DD + c]        = f2bf(sigm(v + bg[c]));
          else if (c < 2048) o_tv[(size_t)r*DD + (c-1024)] = f2bf(tanh_f(v + bv[c-1024]));
          else               o_a [(size_t)r*DD + (c-2048)] = 0.001f + 0.998f*sigm(v + bd[c-2048]);
        }
      }
  } else if constexpr (EPI == 1) {
    #pragma unroll
    for (int m = 0; m < 4; ++m)
      #pragma unroll
      for (int j = 0; j < 2; ++j) {
        int cb = tn*128 + wcol + j*32;               // gate fragment col base (16-aligned, even 16-block)
        int f  = (cb >> 5)*16 + (l & 15);            // paired f index
        #pragma unroll
        for (int i = 0; i < 4; ++i) {
          int r = rbase + m*16 + i;
          float g = acc[m][2*j][i], u = acc[m][2*j+1][i];
          o_h[(size_t)r*FF + f] = f2bf(g * sigm(g) * u);
        }
      }
  } else {
    #pragma unroll
    for (int m = 0; m < 4; ++m)
      #pragma unroll
      for (int n = 0; n < 4; ++n) {
        int c = cbase + n*16;
        #pragma unroll
        for (int i = 0; i < 4; ++i) {
          int r = rbase + m*16 + i;
          size_t idx = (size_t)r*DD + c;
          o_y[idx] = o_y[idx] + acc[m][n][i];
        }
      }
  }
}

// ---------------- chunked causal scan ----------------
// pass1: per (b, chunk, d): A = prod a, X = local scan end (h0=0)
__global__ void scan_pass1(const u16* __restrict__ sg, const u16* __restrict__ tv,
                           const float* __restrict__ ab,
                           float* __restrict__ Ac, float* __restrict__ Xc){
  const int bid = blockIdx.x;
  const int d = ((bid & 3) << 8) + threadIdx.x;   // D/256 = 4
  const int c = (bid >> 2) & (NCH-1);
  const int b = bid >> 7;
  size_t base = ((size_t)b*SS + (size_t)c*LCH)*DD + d;
  float A = 1.f, X = 0.f;
  for (int tt = 0; tt < LCH; ++tt){
    size_t idx = base + (size_t)tt*DD;
    float a  = ab[idx];
    float xs = bf2f(sg[idx]) * bf2f(tv[idx]);
    X = a*X + xs; A *= a;
  }
  size_t o = ((size_t)b*NCH + c)*DD + d;
  Ac[o] = A; Xc[o] = X;
}

// pass2: per (b,d): compose chunk prefixes -> hin per chunk
__global__ void scan_pass2(const float* __restrict__ Ac, const float* __restrict__ Xc,
                           float* __restrict__ hin){
  int gid = blockIdx.x*256 + threadIdx.x;   // 8192 = B*D
  int b = gid >> 10, d = gid & 1023;
  float h = 0.f;
  for (int c = 0; c < NCH; ++c){
    size_t o = ((size_t)b*NCH + c)*DD + d;
    hin[o] = h;
    h = Ac[o]*h + Xc[o];
  }
}

// pass3: re-scan with prefix, fuse residual: y = x + h
__global__ void scan_pass3(const u16* __restrict__ sg, const u16* __restrict__ tv,
                           const float* __restrict__ ab, const float* __restrict__ hin,
                           const float* __restrict__ x, float* __restrict__ y){
  const int bid = blockIdx.x;
  const int d = ((bid & 3) << 8) + threadIdx.x;
  const int c = (bid >> 2) & (NCH-1);
  const int b = bid >> 7;
  size_t base = ((size_t)b*SS + (size_t)c*LCH)*DD + d;
  float h = hin[((size_t)b*NCH + c)*DD + d];
  for (int tt = 0; tt < LCH; ++tt){
    size_t idx = base + (size_t)tt*DD;
    float a  = ab[idx];
    float xs = bf2f(sg[idx]) * bf2f(tv[idx]);
    h = a*h + xs;
    y[idx] = x[idx] + h;
  }
}

// ---------------- launch ----------------
extern "C" void kernel_launch(void* const* d_in, const int* in_sizes, int n_in,
                              void* d_out, int out_size, void* d_ws, size_t ws_size,
                              hipStream_t stream) {
  const float* x     = (const float*)d_in[0];
  const float* rmw   = (const float*)d_in[1];
  const float* rfw   = (const float*)d_in[2];
  const float* Wg    = (const float*)d_in[3];
  const float* bg    = (const float*)d_in[4];
  const float* Wv    = (const float*)d_in[5];
  const float* bv    = (const float*)d_in[6];
  const float* Wd    = (const float*)d_in[7];
  const float* bd    = (const float*)d_in[8];
  const float* Wgate = (const float*)d_in[9];
  const float* Wup   = (const float*)d_in[10];
  const float* Wout  = (const float*)d_in[11];
  float* out = (float*)d_out;

  char* p = (char*)d_ws;
  u16*  xn    = (u16*)p;              p += (size_t)MM*DD*2;        // 33.5MB (reused for xn2)
  u16*  Wgvd  = (u16*)p;              p += (size_t)3072*1024*2;    // 6.3MB
  u16*  Wgu   = (u16*)p;              p += (size_t)6144*1024*2;    // 12.6MB
  u16*  Wo    = (u16*)p;              p += (size_t)1024*3072*2;    // 6.3MB
  char* big   = p;                    p += (size_t)MM*DD*(2+2+4);  // sg,tv (bf16) + a (f32) = 134MB
  u16*  sg    = (u16*)big;
  u16*  tv    = (u16*)(big + (size_t)MM*DD*2);
  float* ab   = (float*)(big + (size_t)MM*DD*4);
  u16*  hbuf  = (u16*)big;            // aliases sg/tv/ab after scan is done (100.7MB <= 134MB)
  float* Ac   = (float*)p;            p += (size_t)BB*NCH*DD*4;    // 1MB
  float* Xc   = (float*)p;            p += (size_t)BB*NCH*DD*4;    // 1MB
  float* hin  = (float*)p;            p += (size_t)BB*NCH*DD*4;    // 1MB

  // weight conversions
  conv_gvd<<<3072, 256, 0, stream>>>(Wg, Wv, Wd, Wgvd);
  conv_gu <<<6144, 256, 0, stream>>>(Wgate, Wup, Wgu);
  conv_cp <<<3072, 256, 0, stream>>>(Wout, Wo);

  // mixer
  rmsnorm_k<<<MM, 256, 0, stream>>>(x, rmw, xn);
  gemm_bt<0><<<dim3(MM/128, 3072/128), 256, 0, stream>>>(xn, Wgvd, 1024,
      bg, bv, bd, sg, tv, ab, nullptr, nullptr);
  scan_pass1<<<BB*NCH*4, 256, 0, stream>>>(sg, tv, ab, Ac, Xc);
  scan_pass2<<<32, 256, 0, stream>>>(Ac, Xc, hin);
  scan_pass3<<<BB*NCH*4, 256, 0, stream>>>(sg, tv, ab, hin, x, out);  // out = y1 = x + scan

  // FFN
  rmsnorm_k<<<MM, 256, 0, stream>>>(out, rfw, xn);
  gemm_bt<1><<<dim3(MM/128, 6144/128), 256, 0, stream>>>(xn, Wgu, 1024,
      nullptr, nullptr, nullptr, nullptr, nullptr, nullptr, hbuf, nullptr);
  gemm_bt<2><<<dim3(MM/128, 1024/128), 256, 0, stream>>>(hbuf, Wo, 3072,
      nullptr, nullptr, nullptr, nullptr, nullptr, nullptr, nullptr, out);
}

// Round 2
// 648.531 us; speedup vs baseline: 1.1278x; 1.1278x over previous
//
#include <hip/hip_runtime.h>
#include <cstdint>
#include <cstddef>

typedef unsigned short u16;
typedef __attribute__((ext_vector_type(4))) float f32x4;
typedef __attribute__((ext_vector_type(8))) short s16x8;

#define BB 8
#define SS 2048
#define DD 1024
#define FF 3072
#define MM (BB*SS)      // 16384 tokens
#define NCH 32          // scan chunks
#define LCH (SS/NCH)    // 64 steps per chunk

__device__ __forceinline__ float bf2f(u16 u){ union{uint32_t i;float f;}v; v.i=((uint32_t)u)<<16; return v.f; }
__device__ __forceinline__ u16 f2bf(float f){ union{float f;uint32_t i;}v; v.f=f; uint32_t r=v.i+0x7FFFu+((v.i>>16)&1u); return (u16)(r>>16); }
__device__ __forceinline__ float sigm(float x){ return 1.f/(1.f+__expf(-x)); }
__device__ __forceinline__ float tanh_f(float x){ return 2.f*sigm(2.f*x)-1.f; }

// ---------------- weight conversion ----------------
// Wg,Wv (16-row interleaved) + Wd -> [3072,1024] bf16.
// rows [32g..32g+15] = Wg[16g..16g+15], rows [32g+16..32g+31] = Wv[16g..16g+15] (g<64),
// rows [2048..3071] = Wd.
__global__ void conv_gvd(const float* __restrict__ Wg, const float* __restrict__ Wv,
                         const float* __restrict__ Wd, u16* __restrict__ out){
  size_t i = ((size_t)blockIdx.x*256 + threadIdx.x)*4;
  int row = (int)(i >> 10); int col = (int)(i & 1023);
  const float* src; int srow;
  if (row < 2048) { int grp = row >> 5, w = row & 31; src = (w < 16) ? Wg : Wv; srow = grp*16 + (w & 15); }
  else            { src = Wd; srow = row - 2048; }
  float4 v = *(const float4*)(src + (size_t)srow*1024 + col);
  ushort4 o; o.x=f2bf(v.x); o.y=f2bf(v.y); o.z=f2bf(v.z); o.w=f2bf(v.w);
  *(ushort4*)(out + i) = o;
}

// W_gate,W_up [3072,1024] -> interleaved [6144,1024] bf16
__global__ void conv_gu(const float* __restrict__ Wgate, const float* __restrict__ Wup,
                        u16* __restrict__ out){
  size_t i = ((size_t)blockIdx.x*256 + threadIdx.x)*4;
  int row = (int)(i >> 10); int col = (int)(i & 1023);
  int group = row >> 5, w = row & 31;
  const float* src = (w < 16) ? Wgate : Wup;
  int srow = group*16 + (w & 15);
  float4 v = *(const float4*)(src + (size_t)srow*1024 + col);
  ushort4 o; o.x=f2bf(v.x); o.y=f2bf(v.y); o.z=f2bf(v.z); o.w=f2bf(v.w);
  *(ushort4*)(out + i) = o;
}

// W_out [1024,3072] f32 -> bf16
__global__ void conv_cp(const float* __restrict__ W, u16* __restrict__ out){
  size_t i = ((size_t)blockIdx.x*256 + threadIdx.x)*4;
  float4 v = *(const float4*)(W + i);
  ushort4 o; o.x=f2bf(v.x); o.y=f2bf(v.y); o.z=f2bf(v.z); o.w=f2bf(v.w);
  *(ushort4*)(out + i) = o;
}

// ---------------- RMSNorm: f32 [M,1024] -> bf16 [M,1024] ----------------
__global__ void rmsnorm_k(const float* __restrict__ x, const float* __restrict__ wgt,
                          u16* __restrict__ out){
  const int row = blockIdx.x, t = threadIdx.x;
  float4 v = ((const float4*)(x + (size_t)row*DD))[t];
  float ss = v.x*v.x + v.y*v.y + v.z*v.z + v.w*v.w;
  #pragma unroll
  for (int o = 32; o > 0; o >>= 1) ss += __shfl_down(ss, o, 64);
  __shared__ float sacc[4];
  if ((t & 63) == 0) sacc[t >> 6] = ss;
  __syncthreads();
  float tot = sacc[0] + sacc[1] + sacc[2] + sacc[3];
  float r = rsqrtf(tot * (1.f/(float)DD) + 1e-6f);
  float4 wv = ((const float4*)wgt)[t];
  ushort4 o; o.x=f2bf(v.x*r*wv.x); o.y=f2bf(v.y*r*wv.y); o.z=f2bf(v.z*r*wv.z); o.w=f2bf(v.w*r*wv.w);
  ((ushort4*)(out + (size_t)row*DD))[t] = o;
}

// ---------------- GEMM: C[M,N] = A[M,K] * B[N,K]^T, bf16 in, f32 acc ----------------
// 128x128 tile, BK=32, 4 waves (2x2), each wave 64x64 = 4x4 fragments of 16x16x32.
// 3-deep LDS pipeline, counted vmcnt (never 0 in steady state), raw s_barrier.
// EPI 0: xs = sigm(g)*tanh(v) for tn<16 (gv interleaved), a for tn>=16.
// EPI 1: SwiGLU pairing -> h bf16.  EPI 2: out += acc (residual already in o_y).
template<int EPI>
__global__ __launch_bounds__(256) void gemm_bt(
    const u16* __restrict__ A, const u16* __restrict__ Bm, int K,
    const float* __restrict__ bg, const float* __restrict__ bv, const float* __restrict__ bd,
    u16* __restrict__ o_xs, float* __restrict__ o_a,
    u16* __restrict__ o_h, float* __restrict__ o_y)
{
  __shared__ u16 lds[3][2][128*32];
  const int tm = blockIdx.x, tn = blockIdx.y;
  const int t = threadIdx.x, w = t >> 6, l = t & 63;
  const int srow = (w << 4) + (l >> 2);      // staging row (+64 for 2nd inst)
  const int scol = (l & 3) << 3;             // staging k-offset (8 bf16)
  const int wrow = ((w >> 1) << 6), wcol = ((w & 1) << 6);

  const u16* ga = A  + (size_t)(tm*128 + srow)*K + scol;
  const u16* gb = Bm + (size_t)(tn*128 + srow)*K + scol;

#define STAGE(buf, kt) do { \
    const u16* pa_ = ga + (size_t)(kt)*32; \
    const u16* pb_ = gb + (size_t)(kt)*32; \
    __builtin_amdgcn_global_load_lds((const __attribute__((address_space(1))) void*)pa_,                   (__attribute__((address_space(3))) void*)&lds[buf][0][w*512],        16, 0, 0); \
    __builtin_amdgcn_global_load_lds((const __attribute__((address_space(1))) void*)(pa_ + (size_t)64*K), (__attribute__((address_space(3))) void*)&lds[buf][0][2048 + w*512], 16, 0, 0); \
    __builtin_amdgcn_global_load_lds((const __attribute__((address_space(1))) void*)pb_,                   (__attribute__((address_space(3))) void*)&lds[buf][1][w*512],        16, 0, 0); \
    __builtin_amdgcn_global_load_lds((const __attribute__((address_space(1))) void*)(pb_ + (size_t)64*K), (__attribute__((address_space(3))) void*)&lds[buf][1][2048 + w*512], 16, 0, 0); \
  } while(0)

  f32x4 acc[4][4] = {};
  const int nk = K / 32;   // >= 32 for all our shapes
  STAGE(0, 0);
  STAGE(1, 1);

  const int ro = ((l & 15) << 5) + ((l >> 4) << 3);  // (row-in-frag)*32 + kslice*8
  for (int kt = 0; kt < nk; ++kt){
    const int cur = kt % 3;
    if (kt + 2 < nk) STAGE((kt + 2) % 3, kt + 2);
    // wait until batch kt has landed (each STAGE = 4 loads/thread)
    if (kt < nk - 2)       asm volatile("s_waitcnt vmcnt(8)" ::: "memory");
    else if (kt == nk - 2) asm volatile("s_waitcnt vmcnt(4)" ::: "memory");
    else                   asm volatile("s_waitcnt vmcnt(0)" ::: "memory");
    __builtin_amdgcn_s_barrier();
    s16x8 af[4], bfr[4];
    #pragma unroll
    for (int m = 0; m < 4; ++m) af[m]  = *(const s16x8*)&lds[cur][0][((wrow + (m<<4)) << 5) + ro];
    #pragma unroll
    for (int n = 0; n < 4; ++n) bfr[n] = *(const s16x8*)&lds[cur][1][((wcol + (n<<4)) << 5) + ro];
    #pragma unroll
    for (int m = 0; m < 4; ++m)
      #pragma unroll
      for (int n = 0; n < 4; ++n)
        acc[m][n] = __builtin_amdgcn_mfma_f32_16x16x32_bf16(af[m], bfr[n], acc[m][n], 0, 0, 0);
    // all ds_reads of buf[cur] must complete before any wave STAGEs into it next iter
    asm volatile("s_waitcnt lgkmcnt(0)" ::: "memory");
    __builtin_amdgcn_s_barrier();
  }
#undef STAGE

  const int rbase = tm*128 + wrow + ((l >> 4) << 2);
  if constexpr (EPI == 0) {
    if (tn < 16) {
      // gv interleaved: frag 2j = g block, frag 2j+1 = v block, feature f
      #pragma unroll
      for (int m = 0; m < 4; ++m)
        #pragma unroll
        for (int j = 0; j < 2; ++j) {
          int f = tn*64 + (wcol >> 1) + j*16 + (l & 15);
          #pragma unroll
          for (int i = 0; i < 4; ++i) {
            int r = rbase + m*16 + i;
            float g = acc[m][2*j][i]   + bg[f];
            float v = acc[m][2*j+1][i] + bv[f];
            o_xs[(size_t)r*DD + f] = f2bf(sigm(g) * tanh_f(v));
          }
        }
    } else {
      #pragma unroll
      for (int m = 0; m < 4; ++m)
        #pragma unroll
        for (int n = 0; n < 4; ++n) {
          int c = (tn-16)*128 + wcol + n*16 + (l & 15);
          #pragma unroll
          for (int i = 0; i < 4; ++i) {
            int r = rbase + m*16 + i;
            o_a[(size_t)r*DD + c] = 0.001f + 0.998f*sigm(acc[m][n][i] + bd[c]);
          }
        }
    }
  } else if constexpr (EPI == 1) {
    #pragma unroll
    for (int m = 0; m < 4; ++m)
      #pragma unroll
      for (int j = 0; j < 2; ++j) {
        int cb = tn*128 + wcol + j*32;               // gate fragment col base
        int f  = (cb >> 5)*16 + (l & 15);            // paired f index
        #pragma unroll
        for (int i = 0; i < 4; ++i) {
          int r = rbase + m*16 + i;
          float g = acc[m][2*j][i], u = acc[m][2*j+1][i];
          o_h[(size_t)r*FF + f] = f2bf(g * sigm(g) * u);
        }
      }
  } else {
    #pragma unroll
    for (int m = 0; m < 4; ++m)
      #pragma unroll
      for (int n = 0; n < 4; ++n) {
        int c = tn*128 + wcol + n*16 + (l & 15);
        #pragma unroll
        for (int i = 0; i < 4; ++i) {
          int r = rbase + m*16 + i;
          size_t idx = (size_t)r*DD + c;
          o_y[idx] = o_y[idx] + acc[m][n][i];
        }
      }
  }
}

// ---------------- chunked causal scan ----------------
// pass1: per (b, chunk, d): A = prod a, X = local scan end (h0=0)
__global__ void scan_pass1(const u16* __restrict__ xs, const float* __restrict__ ab,
                           float* __restrict__ Ac, float* __restrict__ Xc){
  const int bid = blockIdx.x;
  const int d = ((bid & 3) << 8) + threadIdx.x;   // D/256 = 4
  const int c = (bid >> 2) & (NCH-1);
  const int b = bid >> 7;
  size_t base = ((size_t)b*SS + (size_t)c*LCH)*DD + d;
  float A = 1.f, X = 0.f;
  for (int tt = 0; tt < LCH; ++tt){
    size_t idx = base + (size_t)tt*DD;
    float a  = ab[idx];
    X = a*X + bf2f(xs[idx]); A *= a;
  }
  size_t o = ((size_t)b*NCH + c)*DD + d;
  Ac[o] = A; Xc[o] = X;
}

// pass2: per (b,d): compose chunk prefixes -> hin per chunk
__global__ void scan_pass2(const float* __restrict__ Ac, const float* __restrict__ Xc,
                           float* __restrict__ hin){
  int gid = blockIdx.x*256 + threadIdx.x;   // 8192 = B*D
  int b = gid >> 10, d = gid & 1023;
  float h = 0.f;
  for (int c = 0; c < NCH; ++c){
    size_t o = ((size_t)b*NCH + c)*DD + d;
    hin[o] = h;
    h = Ac[o]*h + Xc[o];
  }
}

// pass3: re-scan with prefix, fuse residual: y = x + h
__global__ void scan_pass3(const u16* __restrict__ xs, const float* __restrict__ ab,
                           const float* __restrict__ hin,
                           const float* __restrict__ x, float* __restrict__ y){
  const int bid = blockIdx.x;
  const int d = ((bid & 3) << 8) + threadIdx.x;
  const int c = (bid >> 2) & (NCH-1);
  const int b = bid >> 7;
  size_t base = ((size_t)b*SS + (size_t)c*LCH)*DD + d;
  float h = hin[((size_t)b*NCH + c)*DD + d];
  for (int tt = 0; tt < LCH; ++tt){
    size_t idx = base + (size_t)tt*DD;
    float a  = ab[idx];
    h = a*h + bf2f(xs[idx]);
    y[idx] = x[idx] + h;
  }
}

// ---------------- launch ----------------
extern "C" void kernel_launch(void* const* d_in, const int* in_sizes, int n_in,
                              void* d_out, int out_size, void* d_ws, size_t ws_size,
                              hipStream_t stream) {
  const float* x     = (const float*)d_in[0];
  const float* rmw   = (const float*)d_in[1];
  const float* rfw   = (const float*)d_in[2];
  const float* Wg    = (const float*)d_in[3];
  const float* bg    = (const float*)d_in[4];
  const float* Wv    = (const float*)d_in[5];
  const float* bv    = (const float*)d_in[6];
  const float* Wd    = (const float*)d_in[7];
  const float* bd    = (const float*)d_in[8];
  const float* Wgate = (const float*)d_in[9];
  const float* Wup   = (const float*)d_in[10];
  const float* Wout  = (const float*)d_in[11];
  float* out = (float*)d_out;

  char* p = (char*)d_ws;
  u16*  xn    = (u16*)p;              p += (size_t)MM*DD*2;        // 33.5MB (reused for xn2)
  u16*  Wgvd  = (u16*)p;              p += (size_t)3072*1024*2;    // 6.3MB
  u16*  Wgu   = (u16*)p;              p += (size_t)6144*1024*2;    // 12.6MB
  u16*  Wo    = (u16*)p;              p += (size_t)1024*3072*2;    // 6.3MB
  char* big   = p;                    p += (size_t)MM*FF*2;        // 100.7MB: xs+ab, later hbuf
  u16*  xs    = (u16*)big;                                         // bf16 [M,1024] = 33.5MB
  float* ab   = (float*)(big + (size_t)MM*DD*2);                   // f32 [M,1024] = 67MB
  u16*  hbuf  = (u16*)big;            // aliases xs/ab after scan is done
  float* Ac   = (float*)p;            p += (size_t)BB*NCH*DD*4;    // 1MB
  float* Xc   = (float*)p;            p += (size_t)BB*NCH*DD*4;    // 1MB
  float* hin  = (float*)p;            p += (size_t)BB*NCH*DD*4;    // 1MB

  // weight conversions
  conv_gvd<<<3072, 256, 0, stream>>>(Wg, Wv, Wd, Wgvd);
  conv_gu <<<6144, 256, 0, stream>>>(Wgate, Wup, Wgu);
  conv_cp <<<3072, 256, 0, stream>>>(Wout, Wo);

  // mixer
  rmsnorm_k<<<MM, 256, 0, stream>>>(x, rmw, xn);
  gemm_bt<0><<<dim3(MM/128, 3072/128), 256, 0, stream>>>(xn, Wgvd, 1024,
      bg, bv, bd, xs, ab, nullptr, nullptr);
  scan_pass1<<<BB*NCH*4, 256, 0, stream>>>(xs, ab, Ac, Xc);
  scan_pass2<<<32, 256, 0, stream>>>(Ac, Xc, hin);
  scan_pass3<<<BB*NCH*4, 256, 0, stream>>>(xs, ab, hin, x, out);  // out = y1 = x + scan

  // FFN
  rmsnorm_k<<<MM, 256, 0, stream>>>(out, rfw, xn);
  gemm_bt<1><<<dim3(MM/128, 6144/128), 256, 0, stream>>>(xn, Wgu, 1024,
      nullptr, nullptr, nullptr, nullptr, nullptr, hbuf, nullptr);
  gemm_bt<2><<<dim3(MM/128, 1024/128), 256, 0, stream>>>(hbuf, Wo, 3072,
      nullptr, nullptr, nullptr, nullptr, nullptr, nullptr, out);
}

// Round 3
// 534.935 us; speedup vs baseline: 1.3673x; 1.2124x over previous
//
#include <hip/hip_runtime.h>
#include <cstdint>
#include <cstddef>

typedef unsigned short u16;
typedef __attribute__((ext_vector_type(4))) float f32x4;
typedef __attribute__((ext_vector_type(8))) short s16x8;

#define BB 8
#define SS 2048
#define DD 1024
#define FF 3072
#define MM (BB*SS)      // 16384 tokens
#define NCH 32          // scan chunks
#define LCH (SS/NCH)    // 64 steps per chunk

__device__ __forceinline__ float bf2f(u16 u){ union{uint32_t i;float f;}v; v.i=((uint32_t)u)<<16; return v.f; }
__device__ __forceinline__ u16 f2bf(float f){ union{float f;uint32_t i;}v; v.f=f; uint32_t r=v.i+0x7FFFu+((v.i>>16)&1u); return (u16)(r>>16); }
__device__ __forceinline__ float sigm(float x){ return 1.f/(1.f+__expf(-x)); }
__device__ __forceinline__ float tanh_f(float x){ return 2.f*sigm(2.f*x)-1.f; }

// ---------------- weight conversion ----------------
// Wg,Wv 16-row interleaved + Wd -> [3072,1024] bf16
__global__ void conv_gvd(const float* __restrict__ Wg, const float* __restrict__ Wv,
                         const float* __restrict__ Wd, u16* __restrict__ out){
  size_t i = ((size_t)blockIdx.x*256 + threadIdx.x)*4;
  int row = (int)(i >> 10); int col = (int)(i & 1023);
  const float* src; int srow;
  if (row < 2048) { int grp = row >> 5, w = row & 31; src = (w < 16) ? Wg : Wv; srow = grp*16 + (w & 15); }
  else            { src = Wd; srow = row - 2048; }
  float4 v = *(const float4*)(src + (size_t)srow*1024 + col);
  ushort4 o; o.x=f2bf(v.x); o.y=f2bf(v.y); o.z=f2bf(v.z); o.w=f2bf(v.w);
  *(ushort4*)(out + i) = o;
}

// W_gate,W_up [3072,1024] -> interleaved [6144,1024] bf16
__global__ void conv_gu(const float* __restrict__ Wgate, const float* __restrict__ Wup,
                        u16* __restrict__ out){
  size_t i = ((size_t)blockIdx.x*256 + threadIdx.x)*4;
  int row = (int)(i >> 10); int col = (int)(i & 1023);
  int group = row >> 5, w = row & 31;
  const float* src = (w < 16) ? Wgate : Wup;
  int srow = group*16 + (w & 15);
  float4 v = *(const float4*)(src + (size_t)srow*1024 + col);
  ushort4 o; o.x=f2bf(v.x); o.y=f2bf(v.y); o.z=f2bf(v.z); o.w=f2bf(v.w);
  *(ushort4*)(out + i) = o;
}

// W_out [1024,3072] f32 -> bf16
__global__ void conv_cp(const float* __restrict__ W, u16* __restrict__ out){
  size_t i = ((size_t)blockIdx.x*256 + threadIdx.x)*4;
  float4 v = *(const float4*)(W + i);
  ushort4 o; o.x=f2bf(v.x); o.y=f2bf(v.y); o.z=f2bf(v.z); o.w=f2bf(v.w);
  *(ushort4*)(out + i) = o;
}

// ---------------- RMSNorm: f32 [M,1024] -> bf16 [M,1024] ----------------
__global__ void rmsnorm_k(const float* __restrict__ x, const float* __restrict__ wgt,
                          u16* __restrict__ out){
  const int row = blockIdx.x, t = threadIdx.x;
  float4 v = ((const float4*)(x + (size_t)row*DD))[t];
  float ss = v.x*v.x + v.y*v.y + v.z*v.z + v.w*v.w;
  #pragma unroll
  for (int o = 32; o > 0; o >>= 1) ss += __shfl_down(ss, o, 64);
  __shared__ float sacc[4];
  if ((t & 63) == 0) sacc[t >> 6] = ss;
  __syncthreads();
  float tot = sacc[0] + sacc[1] + sacc[2] + sacc[3];
  float r = rsqrtf(tot * (1.f/(float)DD) + 1e-6f);
  float4 wv = ((const float4*)wgt)[t];
  ushort4 o; o.x=f2bf(v.x*r*wv.x); o.y=f2bf(v.y*r*wv.y); o.z=f2bf(v.z*r*wv.z); o.w=f2bf(v.w*r*wv.w);
  ((ushort4*)(out + (size_t)row*DD))[t] = o;
}

// ---------------- 256x256 8-phase GEMM: C[M,N] = A[M,K]*B[N,K]^T ----------------
// 512 threads = 8 waves (2M x 4N), BK=64, 2 LDS buffers (128 KiB total),
// st-swizzle: 16B slot s at row r holds global slot s^(r&7) (involution, both sides).
// Counted vmcnt(4) at phases 4/8 only; setprio(1) around MFMA cluster.
template<int EPI, int NTN>
__global__ __launch_bounds__(512) void gemm256(
    const u16* __restrict__ A, const u16* __restrict__ Bm, int K,
    const float* __restrict__ bg, const float* __restrict__ bv, const float* __restrict__ bd,
    u16* __restrict__ o_xs, float* __restrict__ o_a,
    u16* __restrict__ o_h, float* __restrict__ o_y)
{
  __shared__ u16 lds[2*32768];   // [buf][A:16384|B:16384] u16, row-major [256][64] per matrix
  const int tid = threadIdx.x, w = tid >> 6, l = tid & 63;
  const int wr = w >> 2, wc = w & 3;
  // bijective XCD swizzle (gridDim.x % 8 == 0 for all our shapes)
  const int nwg = gridDim.x, bid = blockIdx.x;
  const int sw = (bid & 7) * (nwg >> 3) + (bid >> 3);
  const int tm = sw / NTN, tn = sw % NTN;

  // staging: lane covers row w*8+(l>>3), 16B slot (l&7); source slot pre-XORed by row&7
  const int srow  = w*8 + (l >> 3);
  const int sslot = (l & 7) ^ ((l >> 3) & 7);
  const u16* gA = A  + (size_t)(tm*256 + srow)*K + sslot*8;
  const u16* gB = Bm + (size_t)(tn*256 + srow)*K + sslot*8;

#define STAGE_HALF(dbuf, isB, h, tile) do { \
    const u16* gsrc_ = ((isB) ? gB : gA) + ((size_t)(h)*128)*K + (size_t)(tile)*64; \
    u16* ldst_ = &lds[(dbuf)*32768 + (isB)*16384 + (h)*8192 + w*512]; \
    __builtin_amdgcn_global_load_lds((const __attribute__((address_space(1))) void*)gsrc_, \
        (__attribute__((address_space(3))) void*)ldst_, 16, 0, 0); \
    __builtin_amdgcn_global_load_lds((const __attribute__((address_space(1))) void*)(gsrc_ + (size_t)64*K), \
        (__attribute__((address_space(3))) void*)(ldst_ + 4096), 16, 0, 0); \
  } while(0)

  // LDS read addressing (u16 units): row*64 + swizzled_slot*8
  const int aRow = wr*128 + (l & 15);           // + mi*16   (row&7 == l&7)
  const int bRow = wc*64  + (l & 15);           // + ni*16
  const int sl0  = (((l >> 4) ^ (l & 7))) * 8;  // ks=0; ks=1 -> ^32

#define LDA(cb, mi, ks) (*(const s16x8*)&lds[(cb)*32768 + (aRow + (mi)*16)*64 + (sl0 ^ ((ks)*32))])
#define LDB(cb, ni, ks) (*(const s16x8*)&lds[(cb)*32768 + 16384 + (bRow + (ni)*16)*64 + (sl0 ^ ((ks)*32))])

#define LOADB(cb) do { \
    bfr[0][0]=LDB(cb,0,0); bfr[0][1]=LDB(cb,0,1); \
    bfr[1][0]=LDB(cb,1,0); bfr[1][1]=LDB(cb,1,1); \
    bfr[2][0]=LDB(cb,2,0); bfr[2][1]=LDB(cb,2,1); \
    bfr[3][0]=LDB(cb,3,0); bfr[3][1]=LDB(cb,3,1); \
  } while(0)

#define PHASE(cb, mi0, STAGE_STMT, ...) do { \
    s16x8 a00 = LDA(cb, (mi0),   0), a01 = LDA(cb, (mi0),   1); \
    s16x8 a10 = LDA(cb, (mi0)+1, 0), a11 = LDA(cb, (mi0)+1, 1); \
    STAGE_STMT; \
    __builtin_amdgcn_s_barrier(); \
    asm volatile("s_waitcnt lgkmcnt(0)" ::: "memory"); \
    __builtin_amdgcn_s_setprio(1); \
    acc[(mi0)  ][0] = __builtin_amdgcn_mfma_f32_16x16x32_bf16(a00, bfr[0][0], acc[(mi0)  ][0],0,0,0); \
    acc[(mi0)  ][1] = __builtin_amdgcn_mfma_f32_16x16x32_bf16(a00, bfr[1][0], acc[(mi0)  ][1],0,0,0); \
    acc[(mi0)  ][2] = __builtin_amdgcn_mfma_f32_16x16x32_bf16(a00, bfr[2][0], acc[(mi0)  ][2],0,0,0); \
    acc[(mi0)  ][3] = __builtin_amdgcn_mfma_f32_16x16x32_bf16(a00, bfr[3][0], acc[(mi0)  ][3],0,0,0); \
    acc[(mi0)+1][0] = __builtin_amdgcn_mfma_f32_16x16x32_bf16(a10, bfr[0][0], acc[(mi0)+1][0],0,0,0); \
    acc[(mi0)+1][1] = __builtin_amdgcn_mfma_f32_16x16x32_bf16(a10, bfr[1][0], acc[(mi0)+1][1],0,0,0); \
    acc[(mi0)+1][2] = __builtin_amdgcn_mfma_f32_16x16x32_bf16(a10, bfr[2][0], acc[(mi0)+1][2],0,0,0); \
    acc[(mi0)+1][3] = __builtin_amdgcn_mfma_f32_16x16x32_bf16(a10, bfr[3][0], acc[(mi0)+1][3],0,0,0); \
    acc[(mi0)  ][0] = __builtin_amdgcn_mfma_f32_16x16x32_bf16(a01, bfr[0][1], acc[(mi0)  ][0],0,0,0); \
    acc[(mi0)  ][1] = __builtin_amdgcn_mfma_f32_16x16x32_bf16(a01, bfr[1][1], acc[(mi0)  ][1],0,0,0); \
    acc[(mi0)  ][2] = __builtin_amdgcn_mfma_f32_16x16x32_bf16(a01, bfr[2][1], acc[(mi0)  ][2],0,0,0); \
    acc[(mi0)  ][3] = __builtin_amdgcn_mfma_f32_16x16x32_bf16(a01, bfr[3][1], acc[(mi0)  ][3],0,0,0); \
    acc[(mi0)+1][0] = __builtin_amdgcn_mfma_f32_16x16x32_bf16(a11, bfr[0][1], acc[(mi0)+1][0],0,0,0); \
    acc[(mi0)+1][1] = __builtin_amdgcn_mfma_f32_16x16x32_bf16(a11, bfr[1][1], acc[(mi0)+1][1],0,0,0); \
    acc[(mi0)+1][2] = __builtin_amdgcn_mfma_f32_16x16x32_bf16(a11, bfr[2][1], acc[(mi0)+1][2],0,0,0); \
    acc[(mi0)+1][3] = __builtin_amdgcn_mfma_f32_16x16x32_bf16(a11, bfr[3][1], acc[(mi0)+1][3],0,0,0); \
    __builtin_amdgcn_s_setprio(0); \
    __VA_ARGS__; \
    __builtin_amdgcn_s_barrier(); \
  } while(0)

  f32x4 acc[8][4] = {};
  s16x8 bfr[4][2];
  const int nk = K >> 6;   // K/64, even (16 or 48)

  // prologue: tile0 fully into buf0, B of tile1 into buf1 (12 loads)
  STAGE_HALF(0,0,0,0); STAGE_HALF(0,0,1,0);
  STAGE_HALF(0,1,0,0); STAGE_HALF(0,1,1,0);
  STAGE_HALF(1,1,0,1); STAGE_HALF(1,1,1,1);
  asm volatile("s_waitcnt vmcnt(4)" ::: "memory");   // tile0 landed (B(1) may be in flight)
  __builtin_amdgcn_s_barrier();

  for (int it = 0, t = 0; it < (nk >> 1); ++it, t += 2) {
    const int tp1 = t + 1;
    int tp2 = t + 2; if (tp2 >= nk) tp2 -= nk;   // wrapped redundant stage on last iter
    int tp3 = t + 3; if (tp3 >= nk) tp3 -= nk;
    LOADB(0);
    PHASE(0, 0, STAGE_HALF(1,0,0,tp1), );
    PHASE(0, 2, STAGE_HALF(1,0,1,tp1), );
    PHASE(0, 4, STAGE_HALF(0,1,0,tp2), );
    PHASE(0, 6, STAGE_HALF(0,1,1,tp2), asm volatile("s_waitcnt vmcnt(4)" ::: "memory"));
    LOADB(1);
    PHASE(1, 0, STAGE_HALF(0,0,0,tp2), );
    PHASE(1, 2, STAGE_HALF(0,0,1,tp2), );
    PHASE(1, 4, STAGE_HALF(1,1,0,tp3), );
    PHASE(1, 6, STAGE_HALF(1,1,1,tp3), asm volatile("s_waitcnt vmcnt(4)" ::: "memory"));
  }
#undef PHASE
#undef LOADB
#undef LDA
#undef LDB
#undef STAGE_HALF

  // epilogue: C/D layout col = l&15, row = (l>>4)*4 + i
  const int rb = tm*256 + wr*128 + ((l >> 4) << 2);
  const int lc = l & 15;
  if constexpr (EPI == 0) {
    if (tn < 8) {
      #pragma unroll
      for (int mi = 0; mi < 8; ++mi)
        #pragma unroll
        for (int j = 0; j < 2; ++j) {
          int f = tn*128 + wc*32 + j*16 + lc;
          float bgf = bg[f], bvf = bv[f];
          #pragma unroll
          for (int i = 0; i < 4; ++i) {
            int r = rb + mi*16 + i;
            float g = acc[mi][2*j][i]   + bgf;
            float v = acc[mi][2*j+1][i] + bvf;
            o_xs[(size_t)r*DD + f] = f2bf(sigm(g) * tanh_f(v));
          }
        }
    } else {
      #pragma unroll
      for (int mi = 0; mi < 8; ++mi)
        #pragma unroll
        for (int ni = 0; ni < 4; ++ni) {
          int c = (tn-8)*256 + wc*64 + ni*16 + lc;
          float bdc = bd[c];
          #pragma unroll
          for (int i = 0; i < 4; ++i) {
            int r = rb + mi*16 + i;
            o_a[(size_t)r*DD + c] = 0.001f + 0.998f*sigm(acc[mi][ni][i] + bdc);
          }
        }
    }
  } else if constexpr (EPI == 1) {
    #pragma unroll
    for (int mi = 0; mi < 8; ++mi)
      #pragma unroll
      for (int j = 0; j < 2; ++j) {
        int f = tn*128 + wc*32 + j*16 + lc;
        #pragma unroll
        for (int i = 0; i < 4; ++i) {
          int r = rb + mi*16 + i;
          float g = acc[mi][2*j][i], u = acc[mi][2*j+1][i];
          o_h[(size_t)r*FF + f] = f2bf(g * sigm(g) * u);
        }
      }
  } else {
    #pragma unroll
    for (int mi = 0; mi < 8; ++mi)
      #pragma unroll
      for (int ni = 0; ni < 4; ++ni) {
        int c = tn*256 + wc*64 + ni*16 + lc;
        #pragma unroll
        for (int i = 0; i < 4; ++i) {
          int r = rb + mi*16 + i;
          size_t idx = (size_t)r*DD + c;
          o_y[idx] = o_y[idx] + acc[mi][ni][i];
        }
      }
  }
}

// ---------------- chunked causal scan ----------------
__global__ void scan_pass1(const u16* __restrict__ xs, const float* __restrict__ ab,
                           float* __restrict__ Ac, float* __restrict__ Xc){
  const int bid = blockIdx.x;
  const int d = ((bid & 3) << 8) + threadIdx.x;
  const int c = (bid >> 2) & (NCH-1);
  const int b = bid >> 7;
  size_t base = ((size_t)b*SS + (size_t)c*LCH)*DD + d;
  float A = 1.f, X = 0.f;
  for (int tt = 0; tt < LCH; ++tt){
    size_t idx = base + (size_t)tt*DD;
    float a = ab[idx];
    X = a*X + bf2f(xs[idx]); A *= a;
  }
  size_t o = ((size_t)b*NCH + c)*DD + d;
  Ac[o] = A; Xc[o] = X;
}

__global__ void scan_pass2(const float* __restrict__ Ac, const float* __restrict__ Xc,
                           float* __restrict__ hin){
  int gid = blockIdx.x*256 + threadIdx.x;   // 8192 = B*D
  int b = gid >> 10, d = gid & 1023;
  float h = 0.f;
  for (int c = 0; c < NCH; ++c){
    size_t o = ((size_t)b*NCH + c)*DD + d;
    hin[o] = h;
    h = Ac[o]*h + Xc[o];
  }
}

__global__ void scan_pass3(const u16* __restrict__ xs, const float* __restrict__ ab,
                           const float* __restrict__ hin,
                           const float* __restrict__ x, float* __restrict__ y){
  const int bid = blockIdx.x;
  const int d = ((bid & 3) << 8) + threadIdx.x;
  const int c = (bid >> 2) & (NCH-1);
  const int b = bid >> 7;
  size_t base = ((size_t)b*SS + (size_t)c*LCH)*DD + d;
  float h = hin[((size_t)b*NCH + c)*DD + d];
  for (int tt = 0; tt < LCH; ++tt){
    size_t idx = base + (size_t)tt*DD;
    float a = ab[idx];
    h = a*h + bf2f(xs[idx]);
    y[idx] = x[idx] + h;
  }
}

// ---------------- launch ----------------
extern "C" void kernel_launch(void* const* d_in, const int* in_sizes, int n_in,
                              void* d_out, int out_size, void* d_ws, size_t ws_size,
                              hipStream_t stream) {
  const float* x     = (const float*)d_in[0];
  const float* rmw   = (const float*)d_in[1];
  const float* rfw   = (const float*)d_in[2];
  const float* Wg    = (const float*)d_in[3];
  const float* bg    = (const float*)d_in[4];
  const float* Wv    = (const float*)d_in[5];
  const float* bv    = (const float*)d_in[6];
  const float* Wd    = (const float*)d_in[7];
  const float* bd    = (const float*)d_in[8];
  const float* Wgate = (const float*)d_in[9];
  const float* Wup   = (const float*)d_in[10];
  const float* Wout  = (const float*)d_in[11];
  float* out = (float*)d_out;

  char* p = (char*)d_ws;
  u16*  xn    = (u16*)p;              p += (size_t)MM*DD*2;        // 33.5MB (reused for xn2)
  u16*  Wgvd  = (u16*)p;              p += (size_t)3072*1024*2;    // 6.3MB
  u16*  Wgu   = (u16*)p;              p += (size_t)6144*1024*2;    // 12.6MB
  u16*  Wo    = (u16*)p;              p += (size_t)1024*3072*2;    // 6.3MB
  char* big   = p;                    p += (size_t)MM*FF*2;        // 100.7MB: xs+ab, later hbuf
  u16*  xs    = (u16*)big;                                         // bf16 [M,1024]
  float* ab   = (float*)(big + (size_t)MM*DD*2);                   // f32 [M,1024]
  u16*  hbuf  = (u16*)big;            // aliases xs/ab after scan
  float* Ac   = (float*)p;            p += (size_t)BB*NCH*DD*4;
  float* Xc   = (float*)p;            p += (size_t)BB*NCH*DD*4;
  float* hin  = (float*)p;            p += (size_t)BB*NCH*DD*4;

  conv_gvd<<<3072, 256, 0, stream>>>(Wg, Wv, Wd, Wgvd);
  conv_gu <<<6144, 256, 0, stream>>>(Wgate, Wup, Wgu);
  conv_cp <<<3072, 256, 0, stream>>>(Wout, Wo);

  // mixer
  rmsnorm_k<<<MM, 256, 0, stream>>>(x, rmw, xn);
  gemm256<0,12><<<64*12, 512, 0, stream>>>(xn, Wgvd, 1024,
      bg, bv, bd, xs, ab, nullptr, nullptr);
  scan_pass1<<<BB*NCH*4, 256, 0, stream>>>(xs, ab, Ac, Xc);
  scan_pass2<<<32, 256, 0, stream>>>(Ac, Xc, hin);
  scan_pass3<<<BB*NCH*4, 256, 0, stream>>>(xs, ab, hin, x, out);

  // FFN
  rmsnorm_k<<<MM, 256, 0, stream>>>(out, rfw, xn);
  gemm256<1,24><<<64*24, 512, 0, stream>>>(xn, Wgu, 1024,
      nullptr, nullptr, nullptr, nullptr, nullptr, hbuf, nullptr);
  gemm256<2,4><<<64*4, 512, 0, stream>>>(hbuf, Wo, 3072,
      nullptr, nullptr, nullptr, nullptr, nullptr, nullptr, out);
}